// Round 17
// baseline (452.817 us; speedup 1.0000x reference)
//
#include <hip/hip_runtime.h>
#include <hip/hip_bf16.h>
#include <stdint.h>

#define NN 100000
#define EE 1600000
#define RS 4096          // node range per count/fill block
#define NRANGE 25        // ceil(NN/RS)
#define NCH 32           // edge chunks
#define CHSZ (EE/NCH)    // 50000 edges per chunk

#define SC_RZ (-1.44269504f)   // -log2(e): r/z gates use exp2 directly
#define SC_N  (2.88539008f)    // +2*log2(e): n gate tanh via exp2

typedef float f32x4 __attribute__((ext_vector_type(4)));
typedef short bf16x8 __attribute__((ext_vector_type(8)));

#define MFMA(A,B,C) __builtin_amdgcn_mfma_f32_16x16x32_bf16((A),(B),(C),0,0,0)

__device__ __forceinline__ unsigned short f2bf(float f) {
  union { float f; unsigned u; } v; v.f = f;
  unsigned r = v.u + 0x7fffu + ((v.u >> 16) & 1u);
  return (unsigned short)(r >> 16);
}
__device__ __forceinline__ float bflo(unsigned u) {
  union { unsigned u; float f; } v; v.u = u << 16; return v.f;
}
__device__ __forceinline__ float bfhi(unsigned u) {
  union { unsigned u; float f; } v; v.u = u & 0xffff0000u; return v.f;
}

__device__ __forceinline__ unsigned pk2(float lo, float hi) {
  __hip_bfloat162 t = __float22bfloat162_rn(make_float2(lo, hi));
  unsigned r;
  __builtin_memcpy(&r, &t, 4);
  return r;
}
__device__ __forceinline__ bf16x8 packbf(f32x4 a, f32x4 b) {
  union { unsigned u[4]; bf16x8 v; } r;
  r.u[0] = pk2(a[0], a[1]);
  r.u[1] = pk2(a[2], a[3]);
  r.u[2] = pk2(b[0], b[1]);
  r.u[3] = pk2(b[2], b[3]);
  return r.v;
}

__device__ __forceinline__ float exp2fast(float x) {
#if __has_builtin(__builtin_amdgcn_exp2f)
  return __builtin_amdgcn_exp2f(x);
#else
  return exp2f(x);
#endif
}

// ================ k_front: transpose (0..12499) + count (12500..13299) + init (13300..)
__global__ __launch_bounds__(256) void k_front(const float* __restrict__ x,
                                               unsigned short* __restrict__ xT,
                                               float* __restrict__ h0,
                                               const int* __restrict__ graph,
                                               unsigned short* __restrict__ cntS,
                                               unsigned short* __restrict__ cntD,
                                               const float* __restrict__ Wih, const float* __restrict__ Whh,
                                               const float* __restrict__ bih, const float* __restrict__ bhh,
                                               const float* __restrict__ W1, const float* __restrict__ W2,
                                               unsigned short* __restrict__ wihA, unsigned short* __restrict__ whhA,
                                               unsigned short* __restrict__ w1A, unsigned short* __restrict__ w2A,
                                               float* __restrict__ bsum) {
  __shared__ __align__(16) char smem[32768];
  int tid = threadIdx.x;
  unsigned b = blockIdx.x;
  if (b < 12500) {
    float* st = (float*)smem;
    size_t n0 = (size_t)b * 8;
    const float* xb = x + n0 * 768;
#pragma unroll
    for (int i = 0; i < 6; ++i) {
      int w0 = i * 1024 + tid * 4;
      int n = ((w0 >> 8) * 0xAAAB) >> 17;
      int r = w0 - n * 768;
      f32x4 v = *(const f32x4*)(xb + w0);
      float* dp = st + n * 816 + (r >> 4) * 17 + (r & 15);
      dp[0] = v[0]; dp[1] = v[1]; dp[2] = v[2]; dp[3] = v[3];
    }
    __syncthreads();
    if (tid < 128) {
      int hn = tid >> 4, hs = tid & 15;
      h0[(n0 + hn) * 16 + hs] = st[hn * 816 + hs * 17];
    }
#pragma unroll
    for (int j = 0; j < 2; ++j) {
      int o = j * 256 + tid;
      int n = o >> 6, idx = o & 63, t = idx >> 2, k8 = idx & 3;
      const float* sp = st + n * 816 + (16 + 8 * k8) * 17 + t;
      unsigned a0 = f2bf(sp[0])  | ((unsigned)f2bf(sp[17])  << 16);
      unsigned a1 = f2bf(sp[34]) | ((unsigned)f2bf(sp[51])  << 16);
      unsigned a2 = f2bf(sp[68]) | ((unsigned)f2bf(sp[85])  << 16);
      unsigned a3 = f2bf(sp[102])| ((unsigned)f2bf(sp[119]) << 16);
      ((uint4*)xT)[n0 * 64 + o] = uint4{a0, a1, a2, a3};
    }
    return;
  }
  if (b < 13300) {
    unsigned* hS = (unsigned*)smem;
    unsigned* hD = (unsigned*)(smem + 16384);
    int cb = b - 12500;
    int c = cb & (NCH - 1), r = cb >> 5;
    int r0 = r * RS;
    for (int j = tid; j < RS; j += 256) { hS[j] = 0; hD[j] = 0; }
    __syncthreads();
    const int4* sv = (const int4*)(graph + c * CHSZ);
    const int4* dv = (const int4*)(graph + EE + c * CHSZ);
    for (int i = tid; i < CHSZ / 4; i += 256) {
      int4 s4 = sv[i];
      int4 d4 = dv[i];
      int ss[4] = {s4.x, s4.y, s4.z, s4.w};
      int dd[4] = {d4.x, d4.y, d4.z, d4.w};
#pragma unroll
      for (int k = 0; k < 4; ++k) {
        unsigned us = (unsigned)(ss[k] - r0);
        if (us < RS) atomicAdd(&hS[us], 1u);
        unsigned ud = (unsigned)(dd[k] - r0);
        if (ud < RS) atomicAdd(&hD[ud], 1u);
      }
    }
    __syncthreads();
    for (int j = tid; j < RS; j += 256) {
      int n = r0 + j;
      if (n < NN) {
        cntS[(size_t)c * NN + n] = (unsigned short)hS[j];
        cntD[(size_t)c * NN + n] = (unsigned short)hD[j];
      }
    }
    return;
  }
  int idx = (b - 13300) * 256 + tid;
  if (idx < 6144) {
    int e = idx & 7, l = (idx >> 3) & 63, mt = idx >> 9;
    int p = l & 15, q = l >> 4;
    float s = (mt < 8) ? SC_RZ : SC_N;
    wihA[idx] = f2bf(Wih[(mt * 16 + p) * 32 + 8 * q + e] * s);
    return;
  }
  idx -= 6144;
  if (idx < 12288) {
    int e = idx & 7, l = (idx >> 3) & 63, fid = idx >> 9;
    int mt = fid >> 1, kt = fid & 1, p = l & 15, q = l >> 4;
    int j = kt * 32 + 16 * (e >> 2) + 4 * q + (e & 3);
    float s = (mt < 8) ? SC_RZ : SC_N;
    whhA[idx] = f2bf(Whh[(mt * 16 + p) * 64 + j] * s);
    return;
  }
  idx -= 12288;
  if (idx < 8192) {
    int e = idx & 7, l = (idx >> 3) & 63, fid = idx >> 9;
    int mt = fid >> 2, kt = fid & 3, p = l & 15, q = l >> 4;
    w1A[idx] = f2bf(W1[(kt * 32 + 8 * q + e) * 64 + mt * 16 + p]);
    return;
  }
  idx -= 8192;
  if (idx < 4096) {
    int e = idx & 7, l = (idx >> 3) & 63, fid = idx >> 9;
    int mt = fid >> 1, kt = fid & 1, p = l & 15, q = l >> 4;
    int k = kt * 32 + 16 * (e >> 2) + 4 * q + (e & 3);
    w2A[idx] = f2bf(W2[k * 64 + mt * 16 + p]);
    return;
  }
  idx -= 4096;
  if (idx < 192) {
    float s = (idx < 128) ? SC_RZ : SC_N;
    bsum[idx] = (bih[idx] + bhh[idx]) * s;
  }
}

// ================ scan1: degI = sum_c cntD16 -> per-block exclusive scan
__global__ __launch_bounds__(256) void k_scan1(const unsigned short* __restrict__ cntD,
                                               unsigned* __restrict__ degI,
                                               unsigned* __restrict__ offs,
                                               unsigned* __restrict__ bsums) {
  __shared__ unsigned sd[256];
  int tid = threadIdx.x;
  int base = blockIdx.x * 1024 + tid * 4;
  unsigned s0 = 0, s1 = 0, s2 = 0, s3 = 0;
  if (base + 3 < NN) {
#pragma unroll
    for (int c = 0; c < NCH; ++c) {
      uint2 u = *(const uint2*)(cntD + (size_t)c * NN + base);
      s0 += u.x & 0xffffu; s1 += u.x >> 16;
      s2 += u.y & 0xffffu; s3 += u.y >> 16;
    }
  } else {
#pragma unroll
    for (int c = 0; c < NCH; ++c) {
      if (base + 0 < NN) s0 += cntD[(size_t)c * NN + base + 0];
      if (base + 1 < NN) s1 += cntD[(size_t)c * NN + base + 1];
      if (base + 2 < NN) s2 += cntD[(size_t)c * NN + base + 2];
      if (base + 3 < NN) s3 += cntD[(size_t)c * NN + base + 3];
    }
  }
  if (base + 0 < NN) degI[base + 0] = s0;
  if (base + 1 < NN) degI[base + 1] = s1;
  if (base + 2 < NN) degI[base + 2] = s2;
  if (base + 3 < NN) degI[base + 3] = s3;
  unsigned ts = s0 + s1 + s2 + s3;
  sd[tid] = ts;
  __syncthreads();
  for (int o = 1; o < 256; o <<= 1) {
    unsigned xv = (tid >= o) ? sd[tid - o] : 0;
    __syncthreads();
    sd[tid] += xv;
    __syncthreads();
  }
  unsigned run = sd[tid] - ts;
  if (base + 0 < NN) offs[base + 0] = run; run += s0;
  if (base + 1 < NN) offs[base + 1] = run; run += s1;
  if (base + 2 < NN) offs[base + 2] = run; run += s2;
  if (base + 3 < NN) offs[base + 3] = run;
  if (tid == 255) bsums[blockIdx.x] = sd[255];
}

// ================ scan23: finalize offs + curstart + degO + h0 scaling
__global__ __launch_bounds__(256) void k_scan23(unsigned* __restrict__ offs,
                                                const unsigned* __restrict__ bsums,
                                                const unsigned short* __restrict__ cntD,
                                                const unsigned short* __restrict__ cntS,
                                                unsigned* __restrict__ curstart,
                                                unsigned* __restrict__ degO,
                                                float* __restrict__ h0s) {
  __shared__ unsigned sb[128];
  int tid = threadIdx.x;
  if (tid < 128) sb[tid] = (tid < 98) ? bsums[tid] : 0;
  __syncthreads();
  for (int o = 1; o < 128; o <<= 1) {
    unsigned xv = (tid < 128 && tid >= o) ? sb[tid - o] : 0;
    __syncthreads();
    if (tid < 128) sb[tid] += xv;
    __syncthreads();
  }
  int n = blockIdx.x * 256 + tid;
  if (n < NN) {
    int b = n >> 10;
    unsigned add = b ? sb[b - 1] : 0;
    unsigned v = offs[n] + add;
    offs[n] = v;
    unsigned run = v;
    unsigned a = 0;
#pragma unroll
    for (int c = 0; c < NCH; ++c) {
      curstart[(size_t)c * NN + n] = run;
      run += cntD[(size_t)c * NN + n];
      a += cntS[(size_t)c * NN + n];
    }
    degO[n] = a;
    float sc = rsqrtf(fmaxf((float)a, 1.0f));
    f32x4* hp = (f32x4*)(h0s + (size_t)n * 16);
#pragma unroll
    for (int i = 0; i < 4; ++i) {
      f32x4 hv = hp[i];
#pragma unroll
      for (int e = 0; e < 4; ++e) hv[e] *= sc;
      hp[i] = hv;
    }
  }
  if (n == 0) offs[NN] = EE;
}

// ================ k_gf: INTERLEAVED fill (even b: 800) + gru 32-node (odd b: 782)
// fill's latency-bound blocks co-resident with gru's compute blocks for the whole kernel
__global__ __launch_bounds__(256, 2) void k_gf(const unsigned short* __restrict__ xT,
                                               const unsigned short* __restrict__ wihA,
                                               const unsigned short* __restrict__ whhA,
                                               const float* __restrict__ bsum,
                                               const float* __restrict__ bih,
                                               const float* __restrict__ bhh,
                                               unsigned* __restrict__ lstm,
                                               const int* __restrict__ graph,
                                               const unsigned* __restrict__ curstart,
                                               unsigned* __restrict__ eidx) {
  __shared__ __align__(16) char smem[16640];
  int tid = threadIdx.x;
  if ((blockIdx.x & 1) == 0) {
    // ---- fill: per-(range,chunk) scatter via LDS cursor (fill_id 0..799)
    unsigned* cur = (unsigned*)smem;
    int cb = blockIdx.x >> 1;
    int c = cb & (NCH - 1), r = cb >> 5;
    int r0 = r * RS;
    for (int j = tid; j < RS; j += 256) {
      int n = r0 + j;
      cur[j] = (n < NN) ? curstart[(size_t)c * NN + n] : 0u;
    }
    __syncthreads();
    const int4* sv = (const int4*)(graph + c * CHSZ);
    const int4* dv = (const int4*)(graph + EE + c * CHSZ);
    for (int i = tid; i < CHSZ / 4; i += 256) {
      int4 s4 = sv[i];
      int4 d4 = dv[i];
      int ss[4] = {s4.x, s4.y, s4.z, s4.w};
      int dd[4] = {d4.x, d4.y, d4.z, d4.w};
#pragma unroll
      for (int k = 0; k < 4; ++k) {
        unsigned ud = (unsigned)(dd[k] - r0);
        if (ud < RS) {
          unsigned pos = atomicAdd(&cur[ud], 1u);   // LDS atomic
          eidx[pos] = (unsigned)ss[k];
        }
      }
    }
    return;
  }
  // ---- GRU: R14-exact 32 nodes/wave, Whh in regs, clobber = register-budget guard, exp2 gates
  int gb = blockIdx.x >> 1;          // gru block id 0..799 (>=782 idle)
  unsigned short* sWih = (unsigned short*)smem;          // 12288B
  float* sB = (float*)(smem + 12288);                    // 2304B
  for (int i = tid; i < 768; i += 256) ((uint4*)sWih)[i] = ((const uint4*)wihA)[i];
  if (tid < 192) {
    float scn = (tid >= 128) ? SC_N : 1.0f;
    sB[tid] = bsum[tid];
    sB[192 + tid] = bih[tid] * scn;
    sB[384 + tid] = bhh[tid] * scn;
  }
  __syncthreads();
  int wave = tid >> 6, lane = tid & 63;
  int gw = gb * 4 + wave;
  int nb = gw * 32;
  if (nb >= NN) return;
  int p = lane & 15, q = lane >> 4;
  const unsigned short* xw0 = xT + (size_t)(nb + p) * 512 + q * 8;
  const unsigned short* xw1 = xT + (size_t)(nb + 16 + p) * 512 + q * 8;
  const bf16x8* wv = (const bf16x8*)sWih;
  const bf16x8* gh = (const bf16x8*)whhA;
  bf16x8 whhR[24];
#pragma unroll
  for (int fid = 0; fid < 24; ++fid) whhR[fid] = gh[fid * 64 + lane];
  f32x4 hT[2][4] = {};
  bf16x8 hb[2][2] = {};
  uint4 xl0 = *(const uint4*)xw0;
  uint4 xl1 = *(const uint4*)xw1;
#pragma unroll 1
  for (int t = 0; t < 16; ++t) {
    asm volatile("" ::: "memory");  // pin Wih/bias LDS reads in-loop (register-budget guard)
    bf16x8 xb0 = __builtin_bit_cast(bf16x8, xl0);
    bf16x8 xb1 = __builtin_bit_cast(bf16x8, xl1);
    if (t < 15) {
      xl0 = *(const uint4*)(xw0 + (t + 1) * 32);
      xl1 = *(const uint4*)(xw1 + (t + 1) * 32);
    }
#pragma unroll
    for (int i = 0; i < 4; ++i) {
      f32x4 br = *(const f32x4*)(sB + i * 16 + 4 * q);
      f32x4 bz = *(const f32x4*)(sB + 64 + i * 16 + 4 * q);
      f32x4 bn = *(const f32x4*)(sB + 320 + i * 16 + 4 * q);
      f32x4 bh = *(const f32x4*)(sB + 512 + i * 16 + 4 * q);
      f32x4 ar0 = br, ar1 = br, az0 = bz, az1 = bz, an0 = bn, an1 = bn, ah0 = bh, ah1 = bh;
      bf16x8 w;
      w = wv[i * 64 + lane];        ar0 = MFMA(w, xb0, ar0); ar1 = MFMA(w, xb1, ar1);
      w = wv[(4 + i) * 64 + lane];  az0 = MFMA(w, xb0, az0); az1 = MFMA(w, xb1, az1);
      w = wv[(8 + i) * 64 + lane];  an0 = MFMA(w, xb0, an0); an1 = MFMA(w, xb1, an1);
#pragma unroll
      for (int kt = 0; kt < 2; ++kt) {
        ar0 = MFMA(whhR[i * 2 + kt], hb[0][kt], ar0);
        ar1 = MFMA(whhR[i * 2 + kt], hb[1][kt], ar1);
        az0 = MFMA(whhR[8 + i * 2 + kt], hb[0][kt], az0);
        az1 = MFMA(whhR[8 + i * 2 + kt], hb[1][kt], az1);
        ah0 = MFMA(whhR[16 + i * 2 + kt], hb[0][kt], ah0);
        ah1 = MFMA(whhR[16 + i * 2 + kt], hb[1][kt], ah1);
      }
#pragma unroll
      for (int e = 0; e < 4; ++e) {
        float r0 = __builtin_amdgcn_rcpf(1.0f + exp2fast(ar0[e]));
        float z0 = __builtin_amdgcn_rcpf(1.0f + exp2fast(az0[e]));
        float n0 = 1.0f - 2.0f * __builtin_amdgcn_rcpf(exp2fast(an0[e] + r0 * ah0[e]) + 1.0f);
        hT[0][i][e] = n0 + z0 * (hT[0][i][e] - n0);
        float r1 = __builtin_amdgcn_rcpf(1.0f + exp2fast(ar1[e]));
        float z1 = __builtin_amdgcn_rcpf(1.0f + exp2fast(az1[e]));
        float n1 = 1.0f - 2.0f * __builtin_amdgcn_rcpf(exp2fast(an1[e] + r1 * ah1[e]) + 1.0f);
        hT[1][i][e] = n1 + z1 * (hT[1][i][e] - n1);
      }
    }
    hb[0][0] = packbf(hT[0][0], hT[0][1]); hb[0][1] = packbf(hT[0][2], hT[0][3]);
    hb[1][0] = packbf(hT[1][0], hT[1][1]); hb[1][1] = packbf(hT[1][2], hT[1][3]);
  }
  unsigned* lw0 = lstm + (size_t)(nb + p) * 32 + 2 * q;
  unsigned* lw1 = lstm + (size_t)(nb + 16 + p) * 32 + 2 * q;
#pragma unroll
  for (int i = 0; i < 4; ++i) {
    lw0[i * 8]     = pk2(hT[0][i][0], hT[0][i][1]);
    lw0[i * 8 + 1] = pk2(hT[0][i][2], hT[0][i][3]);
    lw1[i * 8]     = pk2(hT[1][i][0], hT[1][i][1]);
    lw1[i * 8 + 1] = pk2(hT[1][i][2], hT[1][i][3]);
  }
}

// ================ conv1: wave-per-node
__global__ __launch_bounds__(256) void k_conv1(const unsigned* __restrict__ offs,
                                               const unsigned* __restrict__ eidx,
                                               const float* __restrict__ h0s,
                                               const unsigned* __restrict__ degI,
                                               const unsigned* __restrict__ degO,
                                               const float* __restrict__ W1,
                                               const float* __restrict__ b1,
                                               unsigned short* __restrict__ h1s) {
  __shared__ float sW[512];
  __shared__ float sb[32];
  __shared__ float sm[4][16];
  int tid = threadIdx.x;
  sW[tid] = W1[tid]; sW[256 + tid] = W1[256 + tid];
  if (tid < 32) sb[tid] = b1[tid];
  int wave = tid >> 6, lane = tid & 63;
  int n = blockIdx.x * 4 + wave;
  int slot = lane >> 4, f = lane & 15;
  unsigned k0 = offs[n], k1 = offs[n + 1];
  float acc = 0.0f;
  for (unsigned k = k0 + slot; k < k1; k += 4)
    acc += h0s[(size_t)eidx[k] * 16 + f];
  acc += __shfl_xor(acc, 16);
  acc += __shfl_xor(acc, 32);
  acc *= rsqrtf(fmaxf((float)degI[n], 1.0f));
  if (slot == 0) sm[wave][f] = acc;
  __syncthreads();
  if (lane < 32) {
    float o = sb[lane];
#pragma unroll
    for (int i = 0; i < 16; ++i) o += sm[wave][i] * sW[i * 32 + lane];
    float sc = rsqrtf(fmaxf((float)degO[n], 1.0f));
    h1s[(size_t)n * 32 + lane] = f2bf(fmaxf(o, 0.0f) * sc);
  }
}

// ================ conv2: wave-per-node
__global__ __launch_bounds__(256) void k_conv2(const unsigned* __restrict__ offs,
                                               const unsigned* __restrict__ eidx,
                                               const unsigned* __restrict__ h1u,
                                               const unsigned* __restrict__ degI,
                                               const float* __restrict__ W2,
                                               const float* __restrict__ b2,
                                               unsigned short* __restrict__ hgnn) {
  __shared__ float sW[2048];
  __shared__ float sb[64];
  __shared__ float sm[4][32];
  int tid = threadIdx.x;
  for (int i = tid; i < 2048; i += 256) sW[i] = W2[i];
  if (tid < 64) sb[tid] = b2[tid];
  int wave = tid >> 6, lane = tid & 63;
  int n = blockIdx.x * 4 + wave;
  int slot = lane >> 4, fu = lane & 15;
  unsigned k0 = offs[n], k1 = offs[n + 1];
  float a0 = 0.0f, a1 = 0.0f;
  for (unsigned k = k0 + slot; k < k1; k += 4) {
    unsigned u = h1u[(size_t)eidx[k] * 16 + fu];
    a0 += bflo(u); a1 += bfhi(u);
  }
  a0 += __shfl_xor(a0, 16); a0 += __shfl_xor(a0, 32);
  a1 += __shfl_xor(a1, 16); a1 += __shfl_xor(a1, 32);
  float sc = rsqrtf(fmaxf((float)degI[n], 1.0f));
  if (slot == 0) { sm[wave][2 * fu] = a0 * sc; sm[wave][2 * fu + 1] = a1 * sc; }
  __syncthreads();
  float o = sb[lane];
#pragma unroll
  for (int i = 0; i < 32; ++i) o += sm[wave][i] * sW[i * 64 + lane];
  hgnn[(size_t)n * 64 + lane] = f2bf(fmaxf(o, 0.0f));
}

// ================ final: LN + lin1(relu) + lin2(relu) + out head, MFMA, 16 nodes/wave
__global__ __launch_bounds__(256) void k_final(const unsigned short* __restrict__ lstm,
                                               const unsigned short* __restrict__ hgnn,
                                               const unsigned short* __restrict__ w1A,
                                               const unsigned short* __restrict__ w2A,
                                               const float* __restrict__ b1,
                                               const float* __restrict__ b2,
                                               const float* __restrict__ lng,
                                               const float* __restrict__ lnb,
                                               const float* __restrict__ outw,
                                               const float* __restrict__ outb,
                                               float* __restrict__ out) {
  __shared__ __align__(16) unsigned short sW1[8192];
  __shared__ __align__(16) unsigned short sW2[4096];
  __shared__ __align__(16) float sP[452];
  int tid = threadIdx.x;
  for (int i = tid; i < 1024; i += 256) ((uint4*)sW1)[i] = ((const uint4*)w1A)[i];
  for (int i = tid; i < 512; i += 256)  ((uint4*)sW2)[i] = ((const uint4*)w2A)[i];
  if (tid < 64) sP[tid] = b1[tid];
  if (tid >= 64 && tid < 128) sP[tid] = b2[tid - 64];
  if (tid < 128) { sP[128 + tid] = lng[tid]; sP[256 + tid] = lnb[tid]; }
  if (tid < 64) sP[384 + tid] = outw[tid];
  if (tid == 0) sP[448] = outb[0];
  __syncthreads();
  int wave = tid >> 6, lane = tid & 63;
  int gw = blockIdx.x * 4 + wave;
  int nb = gw * 16;
  if (nb >= NN) return;
  int s = lane & 15, q = lane >> 4;
  const unsigned short* Ls = lstm + (size_t)(nb + s) * 64;
  const unsigned short* Gs = hgnn + (size_t)(nb + s) * 64;
  float zv[4][8];
#pragma unroll
  for (int blk = 0; blk < 2; ++blk) {
    uint4 lv = *(const uint4*)(Ls + blk * 32 + 8 * q);
    uint4 gv = *(const uint4*)(Gs + blk * 32 + 8 * q);
    unsigned lu[4] = {lv.x, lv.y, lv.z, lv.w};
    unsigned gu[4] = {gv.x, gv.y, gv.z, gv.w};
#pragma unroll
    for (int k = 0; k < 4; ++k) {
      zv[blk][2 * k] = bflo(lu[k]);     zv[blk][2 * k + 1] = bfhi(lu[k]);
      zv[2 + blk][2 * k] = bflo(gu[k]); zv[2 + blk][2 * k + 1] = bfhi(gu[k]);
    }
  }
  float sum = 0.0f, ss = 0.0f;
#pragma unroll
  for (int blk = 0; blk < 4; ++blk)
#pragma unroll
    for (int e = 0; e < 8; ++e) { float v = zv[blk][e]; sum += v; ss += v * v; }
  sum += __shfl_xor(sum, 16); sum += __shfl_xor(sum, 32);
  ss += __shfl_xor(ss, 16);  ss += __shfl_xor(ss, 32);
  float mu = sum * (1.0f / 128.0f);
  float var = ss * (1.0f / 128.0f) - mu * mu;
  float inv = rsqrtf(var + 1e-5f);
  bf16x8 zb[4];
#pragma unroll
  for (int blk = 0; blk < 4; ++blk) {
    bf16x8 r;
#pragma unroll
    for (int e = 0; e < 8; ++e) {
      int f = blk * 32 + 8 * q + e;
      float zn = (zv[blk][e] - mu) * inv * sP[128 + f] + sP[256 + f];
      r[e] = (short)f2bf(zn);
    }
    zb[blk] = r;
  }
  const bf16x8* w1v = (const bf16x8*)sW1;
  const bf16x8* w2v = (const bf16x8*)sW2;
  f32x4 c1[4];
#pragma unroll
  for (int mt = 0; mt < 4; ++mt) {
    c1[mt] = *(const f32x4*)(sP + mt * 16 + 4 * q);
#pragma unroll
    for (int kt = 0; kt < 4; ++kt)
      c1[mt] = MFMA(w1v[(mt * 4 + kt) * 64 + lane], zb[kt], c1[mt]);
#pragma unroll
    for (int e = 0; e < 4; ++e) c1[mt][e] = fmaxf(c1[mt][e], 0.0f);
  }
  bf16x8 h1b[2] = { packbf(c1[0], c1[1]), packbf(c1[2], c1[3]) };
  f32x4 c2[4];
  float partial = 0.0f;
  float* hid = out + 2 * (size_t)NN + (size_t)(nb + s) * 64;
#pragma unroll
  for (int mt = 0; mt < 4; ++mt) {
    c2[mt] = *(const f32x4*)(sP + 64 + mt * 16 + 4 * q);
#pragma unroll
    for (int kt = 0; kt < 2; ++kt)
      c2[mt] = MFMA(w2v[(mt * 2 + kt) * 64 + lane], h1b[kt], c2[mt]);
#pragma unroll
    for (int e = 0; e < 4; ++e) c2[mt][e] = fmaxf(c2[mt][e], 0.0f);
    *(f32x4*)(hid + mt * 16 + 4 * q) = c2[mt];
    f32x4 ow = *(const f32x4*)(sP + 384 + mt * 16 + 4 * q);
#pragma unroll
    for (int e = 0; e < 4; ++e) partial += c2[mt][e] * ow[e];
  }
  partial += __shfl_xor(partial, 16);
  partial += __shfl_xor(partial, 32);
  if (q == 0) {
    float lg = partial + sP[448];
    out[nb + s] = lg;
    out[(size_t)NN + nb + s] = lg;
  }
}

extern "C" void kernel_launch(void* const* d_in, const int* in_sizes, int n_in,
                              void* d_out, int out_size, void* d_ws, size_t ws_size,
                              hipStream_t stream) {
  const float* x   = (const float*)d_in[0];
  const int* graph = (const int*)d_in[1];
  const float* Wih = (const float*)d_in[2];
  const float* Whh = (const float*)d_in[3];
  const float* bih = (const float*)d_in[4];
  const float* bhh = (const float*)d_in[5];
  const float* W1  = (const float*)d_in[6];
  const float* b1  = (const float*)d_in[7];
  const float* W2  = (const float*)d_in[8];
  const float* b2  = (const float*)d_in[9];
  const float* lng = (const float*)d_in[10];
  const float* lnb = (const float*)d_in[11];
  const float* l1W = (const float*)d_in[12];
  const float* l1b = (const float*)d_in[13];
  const float* l2W = (const float*)d_in[14];
  const float* l2b = (const float*)d_in[15];
  const float* oW  = (const float*)d_in[16];
  const float* ob  = (const float*)d_in[17];
  float* out = (float*)d_out;

  char* w = (char*)d_ws;
  unsigned short* xT  = (unsigned short*)(w + 0);
  float* h0s          = (float*)(w + 102400000);
  unsigned* degO      = (unsigned*)(w + 108800000);
  unsigned* degI      = (unsigned*)(w + 109200000);
  unsigned* offs      = (unsigned*)(w + 109600000);
  unsigned* bsums     = (unsigned*)(w + 110400256);
  unsigned* eidx      = (unsigned*)(w + 110400768);
  unsigned short* h1s = (unsigned short*)(w + 116800768);
  unsigned short* hgnn= (unsigned short*)(w + 129600768);
  unsigned* lstm      = (unsigned*)(w + 155200768);
  unsigned short* wihA= (unsigned short*)(w + 180800768);
  unsigned short* whhA= (unsigned short*)(w + 180813056);
  unsigned short* w1A = (unsigned short*)(w + 180837632);
  unsigned short* w2A = (unsigned short*)(w + 180854016);
  float* bsum         = (float*)(w + 180862208);
  if (ws_size < 180862976u) return;
  unsigned short* cntD16 = (unsigned short*)(w + 116800768);
  unsigned short* cntS16 = (unsigned short*)(w + 155200768);
  unsigned* curstart     = (unsigned*)(w + 129600768);

  k_front<<<13421, 256, 0, stream>>>(x, xT, h0s, graph, cntS16, cntD16,
                                     Wih, Whh, bih, bhh, l1W, l2W, wihA, whhA, w1A, w2A, bsum);
  k_scan1<<<98, 256, 0, stream>>>(cntD16, degI, offs, bsums);
  k_scan23<<<391, 256, 0, stream>>>(offs, bsums, cntD16, cntS16, curstart, degO, h0s);
  k_gf<<<1600, 256, 0, stream>>>(xT, wihA, whhA, bsum, bih, bhh, lstm, graph, curstart, eidx);
  k_conv1<<<25000, 256, 0, stream>>>(offs, eidx, h0s, degI, degO, W1, b1, h1s);
  k_conv2<<<25000, 256, 0, stream>>>(offs, eidx, (const unsigned*)h1s, degI, W2, b2, hgnn);
  k_final<<<1563, 256, 0, stream>>>((const unsigned short*)lstm, hgnn,
                                    w1A, w2A, l1b, l2b, lng, lnb, oW, ob, out);
}

// Round 18
// 431.745 us; speedup vs baseline: 1.0488x; 1.0488x over previous
//
#include <hip/hip_runtime.h>
#include <hip/hip_bf16.h>
#include <stdint.h>

#define NN 100000
#define EE 1600000
#define RS 4096          // node range per count/fill block
#define NRANGE 25        // ceil(NN/RS)
#define NCH 32           // edge chunks
#define CHSZ (EE/NCH)    // 50000 edges per chunk

#define SC_RZ (-1.44269504f)   // -log2(e): r/z gates use exp2 directly
#define SC_N  (2.88539008f)    // +2*log2(e): n gate tanh via exp2

typedef float f32x4 __attribute__((ext_vector_type(4)));
typedef short bf16x8 __attribute__((ext_vector_type(8)));

#define MFMA(A,B,C) __builtin_amdgcn_mfma_f32_16x16x32_bf16((A),(B),(C),0,0,0)

__device__ __forceinline__ unsigned short f2bf(float f) {
  union { float f; unsigned u; } v; v.f = f;
  unsigned r = v.u + 0x7fffu + ((v.u >> 16) & 1u);
  return (unsigned short)(r >> 16);
}
__device__ __forceinline__ float bflo(unsigned u) {
  union { unsigned u; float f; } v; v.u = u << 16; return v.f;
}
__device__ __forceinline__ float bfhi(unsigned u) {
  union { unsigned u; float f; } v; v.u = u & 0xffff0000u; return v.f;
}

__device__ __forceinline__ unsigned pk2(float lo, float hi) {
  __hip_bfloat162 t = __float22bfloat162_rn(make_float2(lo, hi));
  unsigned r;
  __builtin_memcpy(&r, &t, 4);
  return r;
}
__device__ __forceinline__ bf16x8 packbf(f32x4 a, f32x4 b) {
  union { unsigned u[4]; bf16x8 v; } r;
  r.u[0] = pk2(a[0], a[1]);
  r.u[1] = pk2(a[2], a[3]);
  r.u[2] = pk2(b[0], b[1]);
  r.u[3] = pk2(b[2], b[3]);
  return r.v;
}

__device__ __forceinline__ float exp2fast(float x) {
#if __has_builtin(__builtin_amdgcn_exp2f)
  return __builtin_amdgcn_exp2f(x);
#else
  return exp2f(x);
#endif
}

// ================ k_front: transpose (0..12499) + count (12500..13299) + init (13300..13420)
__global__ __launch_bounds__(256) void k_front(const float* __restrict__ x,
                                               unsigned short* __restrict__ xT,
                                               float* __restrict__ h0,
                                               const int* __restrict__ graph,
                                               unsigned short* __restrict__ cntS,
                                               unsigned short* __restrict__ cntD,
                                               const float* __restrict__ Wih, const float* __restrict__ Whh,
                                               const float* __restrict__ bih, const float* __restrict__ bhh,
                                               const float* __restrict__ W1, const float* __restrict__ W2,
                                               unsigned short* __restrict__ wihA, unsigned short* __restrict__ whhA,
                                               unsigned short* __restrict__ w1A, unsigned short* __restrict__ w2A,
                                               float* __restrict__ bsum) {
  __shared__ __align__(16) char smem[32768];
  int tid = threadIdx.x;
  unsigned b = blockIdx.x;
  if (b < 12500) {
    // ---- x transpose: 8 nodes/block, full-row coalesced read (HBM roofline)
    float* st = (float*)smem;
    size_t n0 = (size_t)b * 8;
    const float* xb = x + n0 * 768;
#pragma unroll
    for (int i = 0; i < 6; ++i) {
      int w0 = i * 1024 + tid * 4;
      int n = ((w0 >> 8) * 0xAAAB) >> 17;
      int r = w0 - n * 768;
      f32x4 v = *(const f32x4*)(xb + w0);
      float* dp = st + n * 816 + (r >> 4) * 17 + (r & 15);
      dp[0] = v[0]; dp[1] = v[1]; dp[2] = v[2]; dp[3] = v[3];
    }
    __syncthreads();
    if (tid < 128) {
      int hn = tid >> 4, hs = tid & 15;
      h0[(n0 + hn) * 16 + hs] = st[hn * 816 + hs * 17];
    }
#pragma unroll
    for (int j = 0; j < 2; ++j) {
      int o = j * 256 + tid;
      int n = o >> 6, idx = o & 63, t = idx >> 2, k8 = idx & 3;
      const float* sp = st + n * 816 + (16 + 8 * k8) * 17 + t;
      unsigned a0 = f2bf(sp[0])  | ((unsigned)f2bf(sp[17])  << 16);
      unsigned a1 = f2bf(sp[34]) | ((unsigned)f2bf(sp[51])  << 16);
      unsigned a2 = f2bf(sp[68]) | ((unsigned)f2bf(sp[85])  << 16);
      unsigned a3 = f2bf(sp[102])| ((unsigned)f2bf(sp[119]) << 16);
      ((uint4*)xT)[n0 * 64 + o] = uint4{a0, a1, a2, a3};
    }
    return;
  }
  if (b < 13300) {
    // ---- count: per-(range,chunk) LDS dual histogram -> ushort partial counts
    unsigned* hS = (unsigned*)smem;
    unsigned* hD = (unsigned*)(smem + 16384);
    int cb = b - 12500;
    int c = cb & (NCH - 1), r = cb >> 5;
    int r0 = r * RS;
    for (int j = tid; j < RS; j += 256) { hS[j] = 0; hD[j] = 0; }
    __syncthreads();
    const int4* sv = (const int4*)(graph + c * CHSZ);
    const int4* dv = (const int4*)(graph + EE + c * CHSZ);
    for (int i = tid; i < CHSZ / 4; i += 256) {
      int4 s4 = sv[i];
      int4 d4 = dv[i];
      int ss[4] = {s4.x, s4.y, s4.z, s4.w};
      int dd[4] = {d4.x, d4.y, d4.z, d4.w};
#pragma unroll
      for (int k = 0; k < 4; ++k) {
        unsigned us = (unsigned)(ss[k] - r0);
        if (us < RS) atomicAdd(&hS[us], 1u);
        unsigned ud = (unsigned)(dd[k] - r0);
        if (ud < RS) atomicAdd(&hD[ud], 1u);
      }
    }
    __syncthreads();
    for (int j = tid; j < RS; j += 256) {
      int n = r0 + j;
      if (n < NN) {
        cntS[(size_t)c * NN + n] = (unsigned short)hS[j];
        cntD[(size_t)c * NN + n] = (unsigned short)hD[j];
      }
    }
    return;
  }
  // ---- init: weight A-frag tables (r/z rows pre-scaled by -log2e, n rows by 2log2e)
  int idx = (b - 13300) * 256 + tid;
  if (idx < 6144) {
    int e = idx & 7, l = (idx >> 3) & 63, mt = idx >> 9;
    int p = l & 15, q = l >> 4;
    float s = (mt < 8) ? SC_RZ : SC_N;
    wihA[idx] = f2bf(Wih[(mt * 16 + p) * 32 + 8 * q + e] * s);
    return;
  }
  idx -= 6144;
  if (idx < 12288) {
    int e = idx & 7, l = (idx >> 3) & 63, fid = idx >> 9;
    int mt = fid >> 1, kt = fid & 1, p = l & 15, q = l >> 4;
    int j = kt * 32 + 16 * (e >> 2) + 4 * q + (e & 3);
    float s = (mt < 8) ? SC_RZ : SC_N;
    whhA[idx] = f2bf(Whh[(mt * 16 + p) * 64 + j] * s);
    return;
  }
  idx -= 12288;
  if (idx < 8192) {
    int e = idx & 7, l = (idx >> 3) & 63, fid = idx >> 9;
    int mt = fid >> 2, kt = fid & 3, p = l & 15, q = l >> 4;
    w1A[idx] = f2bf(W1[(kt * 32 + 8 * q + e) * 64 + mt * 16 + p]);
    return;
  }
  idx -= 8192;
  if (idx < 4096) {
    int e = idx & 7, l = (idx >> 3) & 63, fid = idx >> 9;
    int mt = fid >> 1, kt = fid & 1, p = l & 15, q = l >> 4;
    int k = kt * 32 + 16 * (e >> 2) + 4 * q + (e & 3);
    w2A[idx] = f2bf(W2[k * 64 + mt * 16 + p]);
    return;
  }
  idx -= 4096;
  if (idx < 192) {
    float s = (idx < 128) ? SC_RZ : SC_N;
    bsum[idx] = (bih[idx] + bhh[idx]) * s;
  }
}

// ================ scan1: degI = sum_c cntD16 (fused reduce) -> per-block exclusive scan
__global__ __launch_bounds__(256) void k_scan1(const unsigned short* __restrict__ cntD,
                                               unsigned* __restrict__ degI,
                                               unsigned* __restrict__ offs,
                                               unsigned* __restrict__ bsums) {
  __shared__ unsigned sd[256];
  int tid = threadIdx.x;
  int base = blockIdx.x * 1024 + tid * 4;
  unsigned s0 = 0, s1 = 0, s2 = 0, s3 = 0;
  if (base + 3 < NN) {
#pragma unroll
    for (int c = 0; c < NCH; ++c) {
      uint2 u = *(const uint2*)(cntD + (size_t)c * NN + base);
      s0 += u.x & 0xffffu; s1 += u.x >> 16;
      s2 += u.y & 0xffffu; s3 += u.y >> 16;
    }
  } else {
#pragma unroll
    for (int c = 0; c < NCH; ++c) {
      if (base + 0 < NN) s0 += cntD[(size_t)c * NN + base + 0];
      if (base + 1 < NN) s1 += cntD[(size_t)c * NN + base + 1];
      if (base + 2 < NN) s2 += cntD[(size_t)c * NN + base + 2];
      if (base + 3 < NN) s3 += cntD[(size_t)c * NN + base + 3];
    }
  }
  if (base + 0 < NN) degI[base + 0] = s0;
  if (base + 1 < NN) degI[base + 1] = s1;
  if (base + 2 < NN) degI[base + 2] = s2;
  if (base + 3 < NN) degI[base + 3] = s3;
  unsigned ts = s0 + s1 + s2 + s3;
  sd[tid] = ts;
  __syncthreads();
  for (int o = 1; o < 256; o <<= 1) {
    unsigned xv = (tid >= o) ? sd[tid - o] : 0;
    __syncthreads();
    sd[tid] += xv;
    __syncthreads();
  }
  unsigned run = sd[tid] - ts;
  if (base + 0 < NN) offs[base + 0] = run; run += s0;
  if (base + 1 < NN) offs[base + 1] = run; run += s1;
  if (base + 2 < NN) offs[base + 2] = run; run += s2;
  if (base + 3 < NN) offs[base + 3] = run;
  if (tid == 255) bsums[blockIdx.x] = sd[255];
}

// ================ scan23: finalize offs + curstart + degO (=sum cntS16, fused) + h0 scaling
__global__ __launch_bounds__(256) void k_scan23(unsigned* __restrict__ offs,
                                                const unsigned* __restrict__ bsums,
                                                const unsigned short* __restrict__ cntD,
                                                const unsigned short* __restrict__ cntS,
                                                unsigned* __restrict__ curstart,
                                                unsigned* __restrict__ degO,
                                                float* __restrict__ h0s) {
  __shared__ unsigned sb[128];
  int tid = threadIdx.x;
  if (tid < 128) sb[tid] = (tid < 98) ? bsums[tid] : 0;
  __syncthreads();
  for (int o = 1; o < 128; o <<= 1) {
    unsigned xv = (tid < 128 && tid >= o) ? sb[tid - o] : 0;
    __syncthreads();
    if (tid < 128) sb[tid] += xv;
    __syncthreads();
  }
  int n = blockIdx.x * 256 + tid;
  if (n < NN) {
    int b = n >> 10;
    unsigned add = b ? sb[b - 1] : 0;
    unsigned v = offs[n] + add;
    offs[n] = v;
    unsigned run = v;
    unsigned a = 0;
#pragma unroll
    for (int c = 0; c < NCH; ++c) {
      curstart[(size_t)c * NN + n] = run;
      run += cntD[(size_t)c * NN + n];
      a += cntS[(size_t)c * NN + n];
    }
    degO[n] = a;
    float sc = rsqrtf(fmaxf((float)a, 1.0f));
    f32x4* hp = (f32x4*)(h0s + (size_t)n * 16);
#pragma unroll
    for (int i = 0; i < 4; ++i) {
      f32x4 hv = hp[i];
#pragma unroll
      for (int e = 0; e < 4; ++e) hv[e] *= sc;
      hp[i] = hv;
    }
  }
  if (n == 0) offs[NN] = EE;
}

// ================ k_gf: gru (blocks 0..781) + fill (782..1581) — independent, co-scheduled
__global__ __launch_bounds__(256, 2) void k_gf(const unsigned short* __restrict__ xT,
                                               const unsigned short* __restrict__ wihA,
                                               const unsigned short* __restrict__ whhA,
                                               const float* __restrict__ bsum,
                                               const float* __restrict__ bih,
                                               const float* __restrict__ bhh,
                                               unsigned* __restrict__ lstm,
                                               const int* __restrict__ graph,
                                               const unsigned* __restrict__ curstart,
                                               unsigned* __restrict__ eidx) {
  __shared__ __align__(16) char smem[16640];
  int tid = threadIdx.x;
  if (blockIdx.x >= 782) {
    // ---- fill: per-(range,chunk) scatter via LDS cursor
    unsigned* cur = (unsigned*)smem;
    int cb = blockIdx.x - 782;
    int c = cb & (NCH - 1), r = cb >> 5;
    int r0 = r * RS;
    for (int j = tid; j < RS; j += 256) {
      int n = r0 + j;
      cur[j] = (n < NN) ? curstart[(size_t)c * NN + n] : 0u;
    }
    __syncthreads();
    const int4* sv = (const int4*)(graph + c * CHSZ);
    const int4* dv = (const int4*)(graph + EE + c * CHSZ);
    for (int i = tid; i < CHSZ / 4; i += 256) {
      int4 s4 = sv[i];
      int4 d4 = dv[i];
      int ss[4] = {s4.x, s4.y, s4.z, s4.w};
      int dd[4] = {d4.x, d4.y, d4.z, d4.w};
#pragma unroll
      for (int k = 0; k < 4; ++k) {
        unsigned ud = (unsigned)(dd[k] - r0);
        if (ud < RS) {
          unsigned pos = atomicAdd(&cur[ud], 1u);   // LDS atomic
          eidx[pos] = (unsigned)ss[k];
        }
      }
    }
    return;
  }
  // ---- GRU: 32 nodes/wave, Whh in regs, clobber = register-budget guard, exp2 gates
  unsigned short* sWih = (unsigned short*)smem;          // 12288B
  float* sB = (float*)(smem + 12288);                    // 2304B
  for (int i = tid; i < 768; i += 256) ((uint4*)sWih)[i] = ((const uint4*)wihA)[i];
  if (tid < 192) {
    float scn = (tid >= 128) ? SC_N : 1.0f;
    sB[tid] = bsum[tid];
    sB[192 + tid] = bih[tid] * scn;
    sB[384 + tid] = bhh[tid] * scn;
  }
  __syncthreads();
  int wave = tid >> 6, lane = tid & 63;
  int gw = blockIdx.x * 4 + wave;
  int nb = gw * 32;
  if (nb >= NN) return;
  int p = lane & 15, q = lane >> 4;
  const unsigned short* xw0 = xT + (size_t)(nb + p) * 512 + q * 8;
  const unsigned short* xw1 = xT + (size_t)(nb + 16 + p) * 512 + q * 8;
  const bf16x8* wv = (const bf16x8*)sWih;
  const bf16x8* gh = (const bf16x8*)whhA;
  bf16x8 whhR[24];
#pragma unroll
  for (int fid = 0; fid < 24; ++fid) whhR[fid] = gh[fid * 64 + lane];
  f32x4 hT[2][4] = {};
  bf16x8 hb[2][2] = {};
  uint4 xl0 = *(const uint4*)xw0;
  uint4 xl1 = *(const uint4*)xw1;
#pragma unroll 1
  for (int t = 0; t < 16; ++t) {
    asm volatile("" ::: "memory");  // pin Wih/bias LDS reads in-loop (register-budget guard)
    bf16x8 xb0 = __builtin_bit_cast(bf16x8, xl0);
    bf16x8 xb1 = __builtin_bit_cast(bf16x8, xl1);
    if (t < 15) {
      xl0 = *(const uint4*)(xw0 + (t + 1) * 32);
      xl1 = *(const uint4*)(xw1 + (t + 1) * 32);
    }
#pragma unroll
    for (int i = 0; i < 4; ++i) {
      f32x4 br = *(const f32x4*)(sB + i * 16 + 4 * q);
      f32x4 bz = *(const f32x4*)(sB + 64 + i * 16 + 4 * q);
      f32x4 bn = *(const f32x4*)(sB + 320 + i * 16 + 4 * q);
      f32x4 bh = *(const f32x4*)(sB + 512 + i * 16 + 4 * q);
      f32x4 ar0 = br, ar1 = br, az0 = bz, az1 = bz, an0 = bn, an1 = bn, ah0 = bh, ah1 = bh;
      bf16x8 w;
      w = wv[i * 64 + lane];        ar0 = MFMA(w, xb0, ar0); ar1 = MFMA(w, xb1, ar1);
      w = wv[(4 + i) * 64 + lane];  az0 = MFMA(w, xb0, az0); az1 = MFMA(w, xb1, az1);
      w = wv[(8 + i) * 64 + lane];  an0 = MFMA(w, xb0, an0); an1 = MFMA(w, xb1, an1);
#pragma unroll
      for (int kt = 0; kt < 2; ++kt) {
        ar0 = MFMA(whhR[i * 2 + kt], hb[0][kt], ar0);
        ar1 = MFMA(whhR[i * 2 + kt], hb[1][kt], ar1);
        az0 = MFMA(whhR[8 + i * 2 + kt], hb[0][kt], az0);
        az1 = MFMA(whhR[8 + i * 2 + kt], hb[1][kt], az1);
        ah0 = MFMA(whhR[16 + i * 2 + kt], hb[0][kt], ah0);
        ah1 = MFMA(whhR[16 + i * 2 + kt], hb[1][kt], ah1);
      }
#pragma unroll
      for (int e = 0; e < 4; ++e) {
        float r0 = __builtin_amdgcn_rcpf(1.0f + exp2fast(ar0[e]));
        float z0 = __builtin_amdgcn_rcpf(1.0f + exp2fast(az0[e]));
        float n0 = 1.0f - 2.0f * __builtin_amdgcn_rcpf(exp2fast(an0[e] + r0 * ah0[e]) + 1.0f);
        hT[0][i][e] = n0 + z0 * (hT[0][i][e] - n0);
        float r1 = __builtin_amdgcn_rcpf(1.0f + exp2fast(ar1[e]));
        float z1 = __builtin_amdgcn_rcpf(1.0f + exp2fast(az1[e]));
        float n1 = 1.0f - 2.0f * __builtin_amdgcn_rcpf(exp2fast(an1[e] + r1 * ah1[e]) + 1.0f);
        hT[1][i][e] = n1 + z1 * (hT[1][i][e] - n1);
      }
    }
    hb[0][0] = packbf(hT[0][0], hT[0][1]); hb[0][1] = packbf(hT[0][2], hT[0][3]);
    hb[1][0] = packbf(hT[1][0], hT[1][1]); hb[1][1] = packbf(hT[1][2], hT[1][3]);
  }
  unsigned* lw0 = lstm + (size_t)(nb + p) * 32 + 2 * q;
  unsigned* lw1 = lstm + (size_t)(nb + 16 + p) * 32 + 2 * q;
#pragma unroll
  for (int i = 0; i < 4; ++i) {
    lw0[i * 8]     = pk2(hT[0][i][0], hT[0][i][1]);
    lw0[i * 8 + 1] = pk2(hT[0][i][2], hT[0][i][3]);
    lw1[i * 8]     = pk2(hT[1][i][0], hT[1][i][1]);
    lw1[i * 8 + 1] = pk2(hT[1][i][2], hT[1][i][3]);
  }
}

// ================ conv1: wave-per-node
__global__ __launch_bounds__(256) void k_conv1(const unsigned* __restrict__ offs,
                                               const unsigned* __restrict__ eidx,
                                               const float* __restrict__ h0s,
                                               const unsigned* __restrict__ degI,
                                               const unsigned* __restrict__ degO,
                                               const float* __restrict__ W1,
                                               const float* __restrict__ b1,
                                               unsigned short* __restrict__ h1s) {
  __shared__ float sW[512];
  __shared__ float sb[32];
  __shared__ float sm[4][16];
  int tid = threadIdx.x;
  sW[tid] = W1[tid]; sW[256 + tid] = W1[256 + tid];
  if (tid < 32) sb[tid] = b1[tid];
  int wave = tid >> 6, lane = tid & 63;
  int n = blockIdx.x * 4 + wave;
  int slot = lane >> 4, f = lane & 15;
  unsigned k0 = offs[n], k1 = offs[n + 1];
  float acc = 0.0f;
  for (unsigned k = k0 + slot; k < k1; k += 4)
    acc += h0s[(size_t)eidx[k] * 16 + f];
  acc += __shfl_xor(acc, 16);
  acc += __shfl_xor(acc, 32);
  acc *= rsqrtf(fmaxf((float)degI[n], 1.0f));
  if (slot == 0) sm[wave][f] = acc;
  __syncthreads();
  if (lane < 32) {
    float o = sb[lane];
#pragma unroll
    for (int i = 0; i < 16; ++i) o += sm[wave][i] * sW[i * 32 + lane];
    float sc = rsqrtf(fmaxf((float)degO[n], 1.0f));
    h1s[(size_t)n * 32 + lane] = f2bf(fmaxf(o, 0.0f) * sc);
  }
}

// ================ conv2: wave-per-node
__global__ __launch_bounds__(256) void k_conv2(const unsigned* __restrict__ offs,
                                               const unsigned* __restrict__ eidx,
                                               const unsigned* __restrict__ h1u,
                                               const unsigned* __restrict__ degI,
                                               const float* __restrict__ W2,
                                               const float* __restrict__ b2,
                                               unsigned short* __restrict__ hgnn) {
  __shared__ float sW[2048];
  __shared__ float sb[64];
  __shared__ float sm[4][32];
  int tid = threadIdx.x;
  for (int i = tid; i < 2048; i += 256) sW[i] = W2[i];
  if (tid < 64) sb[tid] = b2[tid];
  int wave = tid >> 6, lane = tid & 63;
  int n = blockIdx.x * 4 + wave;
  int slot = lane >> 4, fu = lane & 15;
  unsigned k0 = offs[n], k1 = offs[n + 1];
  float a0 = 0.0f, a1 = 0.0f;
  for (unsigned k = k0 + slot; k < k1; k += 4) {
    unsigned u = h1u[(size_t)eidx[k] * 16 + fu];
    a0 += bflo(u); a1 += bfhi(u);
  }
  a0 += __shfl_xor(a0, 16); a0 += __shfl_xor(a0, 32);
  a1 += __shfl_xor(a1, 16); a1 += __shfl_xor(a1, 32);
  float sc = rsqrtf(fmaxf((float)degI[n], 1.0f));
  if (slot == 0) { sm[wave][2 * fu] = a0 * sc; sm[wave][2 * fu + 1] = a1 * sc; }
  __syncthreads();
  float o = sb[lane];
#pragma unroll
  for (int i = 0; i < 32; ++i) o += sm[wave][i] * sW[i * 64 + lane];
  hgnn[(size_t)n * 64 + lane] = f2bf(fmaxf(o, 0.0f));
}

// ================ final: LN + lin1(relu) + lin2(relu) + out head, MFMA, 16 nodes/wave
__global__ __launch_bounds__(256) void k_final(const unsigned short* __restrict__ lstm,
                                               const unsigned short* __restrict__ hgnn,
                                               const unsigned short* __restrict__ w1A,
                                               const unsigned short* __restrict__ w2A,
                                               const float* __restrict__ b1,
                                               const float* __restrict__ b2,
                                               const float* __restrict__ lng,
                                               const float* __restrict__ lnb,
                                               const float* __restrict__ outw,
                                               const float* __restrict__ outb,
                                               float* __restrict__ out) {
  __shared__ __align__(16) unsigned short sW1[8192];
  __shared__ __align__(16) unsigned short sW2[4096];
  __shared__ __align__(16) float sP[452];
  int tid = threadIdx.x;
  for (int i = tid; i < 1024; i += 256) ((uint4*)sW1)[i] = ((const uint4*)w1A)[i];
  for (int i = tid; i < 512; i += 256)  ((uint4*)sW2)[i] = ((const uint4*)w2A)[i];
  if (tid < 64) sP[tid] = b1[tid];
  if (tid >= 64 && tid < 128) sP[tid] = b2[tid - 64];
  if (tid < 128) { sP[128 + tid] = lng[tid]; sP[256 + tid] = lnb[tid]; }
  if (tid < 64) sP[384 + tid] = outw[tid];
  if (tid == 0) sP[448] = outb[0];
  __syncthreads();
  int wave = tid >> 6, lane = tid & 63;
  int gw = blockIdx.x * 4 + wave;
  int nb = gw * 16;
  if (nb >= NN) return;
  int s = lane & 15, q = lane >> 4;
  const unsigned short* Ls = lstm + (size_t)(nb + s) * 64;
  const unsigned short* Gs = hgnn + (size_t)(nb + s) * 64;
  float zv[4][8];
#pragma unroll
  for (int blk = 0; blk < 2; ++blk) {
    uint4 lv = *(const uint4*)(Ls + blk * 32 + 8 * q);
    uint4 gv = *(const uint4*)(Gs + blk * 32 + 8 * q);
    unsigned lu[4] = {lv.x, lv.y, lv.z, lv.w};
    unsigned gu[4] = {gv.x, gv.y, gv.z, gv.w};
#pragma unroll
    for (int k = 0; k < 4; ++k) {
      zv[blk][2 * k] = bflo(lu[k]);     zv[blk][2 * k + 1] = bfhi(lu[k]);
      zv[2 + blk][2 * k] = bflo(gu[k]); zv[2 + blk][2 * k + 1] = bfhi(gu[k]);
    }
  }
  float sum = 0.0f, ss = 0.0f;
#pragma unroll
  for (int blk = 0; blk < 4; ++blk)
#pragma unroll
    for (int e = 0; e < 8; ++e) { float v = zv[blk][e]; sum += v; ss += v * v; }
  sum += __shfl_xor(sum, 16); sum += __shfl_xor(sum, 32);
  ss += __shfl_xor(ss, 16);  ss += __shfl_xor(ss, 32);
  float mu = sum * (1.0f / 128.0f);
  float var = ss * (1.0f / 128.0f) - mu * mu;
  float inv = rsqrtf(var + 1e-5f);
  bf16x8 zb[4];
#pragma unroll
  for (int blk = 0; blk < 4; ++blk) {
    bf16x8 r;
#pragma unroll
    for (int e = 0; e < 8; ++e) {
      int f = blk * 32 + 8 * q + e;
      float zn = (zv[blk][e] - mu) * inv * sP[128 + f] + sP[256 + f];
      r[e] = (short)f2bf(zn);
    }
    zb[blk] = r;
  }
  const bf16x8* w1v = (const bf16x8*)sW1;
  const bf16x8* w2v = (const bf16x8*)sW2;
  f32x4 c1[4];
#pragma unroll
  for (int mt = 0; mt < 4; ++mt) {
    c1[mt] = *(const f32x4*)(sP + mt * 16 + 4 * q);
#pragma unroll
    for (int kt = 0; kt < 4; ++kt)
      c1[mt] = MFMA(w1v[(mt * 4 + kt) * 64 + lane], zb[kt], c1[mt]);
#pragma unroll
    for (int e = 0; e < 4; ++e) c1[mt][e] = fmaxf(c1[mt][e], 0.0f);
  }
  bf16x8 h1b[2] = { packbf(c1[0], c1[1]), packbf(c1[2], c1[3]) };
  f32x4 c2[4];
  float partial = 0.0f;
  float* hid = out + 2 * (size_t)NN + (size_t)(nb + s) * 64;
#pragma unroll
  for (int mt = 0; mt < 4; ++mt) {
    c2[mt] = *(const f32x4*)(sP + 64 + mt * 16 + 4 * q);
#pragma unroll
    for (int kt = 0; kt < 2; ++kt)
      c2[mt] = MFMA(w2v[(mt * 2 + kt) * 64 + lane], h1b[kt], c2[mt]);
#pragma unroll
    for (int e = 0; e < 4; ++e) c2[mt][e] = fmaxf(c2[mt][e], 0.0f);
    *(f32x4*)(hid + mt * 16 + 4 * q) = c2[mt];
    f32x4 ow = *(const f32x4*)(sP + 384 + mt * 16 + 4 * q);
#pragma unroll
    for (int e = 0; e < 4; ++e) partial += c2[mt][e] * ow[e];
  }
  partial += __shfl_xor(partial, 16);
  partial += __shfl_xor(partial, 32);
  if (q == 0) {
    float lg = partial + sP[448];
    out[nb + s] = lg;
    out[(size_t)NN + nb + s] = lg;
  }
}

extern "C" void kernel_launch(void* const* d_in, const int* in_sizes, int n_in,
                              void* d_out, int out_size, void* d_ws, size_t ws_size,
                              hipStream_t stream) {
  const float* x   = (const float*)d_in[0];
  const int* graph = (const int*)d_in[1];
  const float* Wih = (const float*)d_in[2];
  const float* Whh = (const float*)d_in[3];
  const float* bih = (const float*)d_in[4];
  const float* bhh = (const float*)d_in[5];
  const float* W1  = (const float*)d_in[6];
  const float* b1  = (const float*)d_in[7];
  const float* W2  = (const float*)d_in[8];
  const float* b2  = (const float*)d_in[9];
  const float* lng = (const float*)d_in[10];
  const float* lnb = (const float*)d_in[11];
  const float* l1W = (const float*)d_in[12];
  const float* l1b = (const float*)d_in[13];
  const float* l2W = (const float*)d_in[14];
  const float* l2b = (const float*)d_in[15];
  const float* oW  = (const float*)d_in[16];
  const float* ob  = (const float*)d_in[17];
  float* out = (float*)d_out;

  char* w = (char*)d_ws;
  unsigned short* xT  = (unsigned short*)(w + 0);
  float* h0s          = (float*)(w + 102400000);
  unsigned* degO      = (unsigned*)(w + 108800000);
  unsigned* degI      = (unsigned*)(w + 109200000);
  unsigned* offs      = (unsigned*)(w + 109600000);
  unsigned* bsums     = (unsigned*)(w + 110400256);
  unsigned* eidx      = (unsigned*)(w + 110400768);
  unsigned short* h1s = (unsigned short*)(w + 116800768);
  unsigned short* hgnn= (unsigned short*)(w + 129600768);
  unsigned* lstm      = (unsigned*)(w + 155200768);
  unsigned short* wihA= (unsigned short*)(w + 180800768);
  unsigned short* whhA= (unsigned short*)(w + 180813056);
  unsigned short* w1A = (unsigned short*)(w + 180837632);
  unsigned short* w2A = (unsigned short*)(w + 180854016);
  float* bsum         = (float*)(w + 180862208);
  if (ws_size < 180862976u) return;
  unsigned short* cntD16 = (unsigned short*)(w + 116800768);
  unsigned short* cntS16 = (unsigned short*)(w + 155200768);
  unsigned* curstart     = (unsigned*)(w + 129600768);

  k_front<<<13421, 256, 0, stream>>>(x, xT, h0s, graph, cntS16, cntD16,
                                     Wih, Whh, bih, bhh, l1W, l2W, wihA, whhA, w1A, w2A, bsum);
  k_scan1<<<98, 256, 0, stream>>>(cntD16, degI, offs, bsums);
  k_scan23<<<391, 256, 0, stream>>>(offs, bsums, cntD16, cntS16, curstart, degO, h0s);
  k_gf<<<1582, 256, 0, stream>>>(xT, wihA, whhA, bsum, bih, bhh, lstm, graph, curstart, eidx);
  k_conv1<<<25000, 256, 0, stream>>>(offs, eidx, h0s, degI, degO, W1, b1, h1s);
  k_conv2<<<25000, 256, 0, stream>>>(offs, eidx, (const unsigned*)h1s, degI, W2, b2, hgnn);
  k_final<<<1563, 256, 0, stream>>>((const unsigned short*)lstm, hgnn,
                                    w1A, w2A, l1b, l2b, lng, lnb, oW, ob, out);
}